// Round 13
// baseline (662.963 us; speedup 1.0000x reference)
//
#include <hip/hip_runtime.h>
#include <math.h>

#define N_NODES 100000
#define N_EDGES 1600000
#define NBUK 391          // ceil(N/256) scan blocks of 256 consecutive nodes
#define PBLK16 3128       // 8 XCD-slots: 4 planes x 782 chunks of 128 nodes
#define EBLK 1563         // ceil(E/4/256) blocks for edge-parallel kernels (4 edges/thread)

typedef unsigned short u16;
typedef unsigned char u8;
typedef __bf16 bf16x8 __attribute__((ext_vector_type(8)));
typedef float f32x4 __attribute__((ext_vector_type(4)));
typedef float f32x2 __attribute__((ext_vector_type(2)));

// ---- workspace layout (bytes), 16B-aligned ----
#define OFF_RP      0u          // int[N+1]
#define OFF_INVDEG  400016u     // float[N]
#define OFF_BHIST   800016u     // int[392] scan-block totals
#define OFF_BBASE   801600u     // int[392]
#define OFF_GCUR    803200u     // int[391] (unused, layout stability)
#define OFF_PCTR    804800u     // int[64]  (unused, layout stability)
#define OFF_DEG     805056u     // int[N] per-node degree   (reuses old pairs region)
#define OFF_CUR     1205056u    // int[N] scatter cursors
#define OFF_COL     13605056u   // int[E]
#define OFF_PACK    20005056u   // u16[131072] packed bf16 weight fragments
#define OFF_INP     20267200u   // u16[N*128] residual (pre-relu inProj), bf16
#define OFF_H       45867200u   // u16[N*128] h (in-place across layers), bf16, row-major
#define OFF_H8A     71467200u   // u8[4][N][32] fp8 copy of h, PLANE-major, buffer A
#define OFF_H8B     84267200u   // u8[4][N][32] fp8 copy, PLANE-major, buffer B
#define OFF_GL      97067200u   // u16[4][N][16] projected neighbor logits, PLANE-major bf16
#define OFF_GR      109867200u  // u16[N*64] projected root logits, bf16, row-major
#define OFF_MEAN    122667200u  // u16[4][N][32] aggregated mean, PLANE-major bf16
                                // (reused as float[N][64] partial for output stage)
#define WS_NEEDED   148267200u

// packed-weight element offsets (u16 units)
#define PK_WP   0
#define PK_WL   16384
#define PK_WR   65536
#define PK_WLO  114688
#define PK_WRO  122880

__device__ __forceinline__ float bfl(unsigned u) {
  union { unsigned i; float f; } v; v.i = u << 16; return v.f;
}
__device__ __forceinline__ float bfh(unsigned u) {
  union { unsigned i; float f; } v; v.i = u & 0xFFFF0000u; return v.f;
}
__device__ __forceinline__ u16 f2b(float f) {       // RTNE
  union { float f; unsigned i; } v; v.f = f;
  unsigned r = (v.i + 0x7FFFu + ((v.i >> 16) & 1u)) >> 16;
  return (u16)r;
}

// ---------------- pack fp32 weights -> bf16 MFMA B-fragments ----------------
__global__ __launch_bounds__(256) void pack_weights_k(
    const float* __restrict__ Wp, const float* __restrict__ Wl,
    const float* __restrict__ Wr, const float* __restrict__ Wlo,
    const float* __restrict__ Wro, u16* __restrict__ P) {
  int t = blockIdx.x * 256 + threadIdx.x;
  if (t >= 16384) return;
  const float* W; u16* dst; int j; int NT;
  if (t < 2048)        { W = Wp;                    dst = P + PK_WP;                j = t;                 NT = 8; }
  else if (t < 8192)   { int m = (t - 2048) >> 11;  j = (t - 2048) & 2047;
                         W = Wl + (m << 14);        dst = P + PK_WL + (m << 14);    NT = 8; }
  else if (t < 14336)  { int m = (t - 8192) >> 11;  j = (t - 8192) & 2047;
                         W = Wr + (m << 14);        dst = P + PK_WR + (m << 14);    NT = 8; }
  else if (t < 15360)  { j = t - 14336;             W = Wlo;  dst = P + PK_WLO;     NT = 4; }
  else                 { j = t - 15360;             W = Wro;  dst = P + PK_WRO;     NT = 4; }
  int lane = j & 63;
  int nt, kt;
  if (NT == 8) { nt = (j >> 6) & 7; kt = j >> 9; }
  else         { nt = (j >> 6) & 3; kt = j >> 8; }
  int n  = nt * 16 + (lane & 15);
  int k0 = kt * 32 + ((lane >> 4) << 3);
  const float* s = W + n * 128 + k0;
  ushort4 lo = make_ushort4(f2b(s[0]), f2b(s[1]), f2b(s[2]), f2b(s[3]));
  ushort4 hi = make_ushort4(f2b(s[4]), f2b(s[5]), f2b(s[6]), f2b(s[7]));
  *(ushort4*)(dst + j * 8)     = lo;
  *(ushort4*)(dst + j * 8 + 4) = hi;
}

// ---------- per-node degree: 1.6M device-scope atomics into 400KB table ----------
__global__ __launch_bounds__(256) void deg_k(const int* __restrict__ dst,
                                             int* __restrict__ deg) {
  int i = (blockIdx.x * 256 + threadIdx.x) * 4;
  if (i + 3 >= N_EDGES) {
    for (; i < N_EDGES; i++) atomicAdd(&deg[dst[i]], 1);
    return;
  }
  int4 d = *(const int4*)(dst + i);
  atomicAdd(&deg[d.x], 1);
  atomicAdd(&deg[d.y], 1);
  atomicAdd(&deg[d.z], 1);
  atomicAdd(&deg[d.w], 1);
}

// ---------- scan level 1: per-256-node block exclusive scan + block totals ----------
__global__ __launch_bounds__(256) void scan1_k(const int* __restrict__ deg,
                                               int* __restrict__ rp,
                                               int* __restrict__ bhist) {
  __shared__ int s[256];
  int b = blockIdx.x, t = threadIdx.x;
  int node = b * 256 + t;
  int v = (node < N_NODES) ? deg[node] : 0;
  s[t] = v;
  __syncthreads();
  for (int off = 1; off < 256; off <<= 1) {
    int u = (t >= off) ? s[t - off] : 0;
    __syncthreads();
    s[t] += u;
    __syncthreads();
  }
  if (t == 255) bhist[b] = s[255];
  if (node < N_NODES) rp[node] = s[t] - v;   // exclusive within block
}

// ---------- single-block scan of block totals ----------
__global__ __launch_bounds__(512) void bscan_k(const int* __restrict__ bhist,
                                               int* __restrict__ bbase,
                                               int* __restrict__ rp) {
  __shared__ int s[512];
  int t = threadIdx.x;
  int v = (t < NBUK) ? bhist[t] : 0;
  s[t] = v;
  __syncthreads();
  for (int off = 1; off < 512; off <<= 1) {
    int u = (t >= off) ? s[t - off] : 0;
    __syncthreads();
    s[t] += u;
    __syncthreads();
  }
  if (t < NBUK) bbase[t] = s[t] - v;
  if (t == NBUK - 1) rp[N_NODES] = s[t];
}

// ---------- scan level 2: add block base; init cursors + invdeg ----------
__global__ __launch_bounds__(256) void scan2_k(const int* __restrict__ bbase,
                                               const int* __restrict__ deg,
                                               int* __restrict__ rp,
                                               int* __restrict__ cur,
                                               float* __restrict__ invdeg) {
  int b = blockIdx.x, t = threadIdx.x;
  int node = b * 256 + t;
  if (node >= N_NODES) return;
  int r = rp[node] + bbase[b];
  rp[node] = r;
  cur[node] = r;
  int d = deg[node];
  invdeg[node] = 1.0f / (float)(d > 1 ? d : 1);
}

// ---------- direct CSR scatter: col[atomicAdd(cur[dst])] = src ----------
__global__ __launch_bounds__(256) void scatter_k(const int* __restrict__ src,
                                                 const int* __restrict__ dst,
                                                 int* __restrict__ cur,
                                                 int* __restrict__ col) {
  int i = (blockIdx.x * 256 + threadIdx.x) * 4;
  if (i + 3 >= N_EDGES) {
    for (; i < N_EDGES; i++) {
      int p = atomicAdd(&cur[dst[i]], 1);
      col[p] = src[i];
    }
    return;
  }
  int4 s4 = *(const int4*)(src + i);
  int4 d4 = *(const int4*)(dst + i);
  int p0 = atomicAdd(&cur[d4.x], 1);
  int p1 = atomicAdd(&cur[d4.y], 1);
  int p2 = atomicAdd(&cur[d4.z], 1);
  int p3 = atomicAdd(&cur[d4.w], 1);
  col[p0] = s4.x;
  col[p1] = s4.y;
  col[p2] = s4.z;
  col[p3] = s4.w;
}

// ------- plane-major mean aggregation: 2 lanes x 16B per 32B plane row -------
// Gather family declared rooflined at ~53us (R10): invariant to layout, lane
// width, and MLP depth -> ~20 cy/edge/CU per-request floor. Keep best variant.
__global__ __launch_bounds__(256) void aggregate_plane16_k(
    const u8* __restrict__ h8, const int* __restrict__ rp,
    const int* __restrict__ col, const float* __restrict__ invdeg,
    u16* __restrict__ mean) {
  int b = blockIdx.x;
  int plane = (b & 7) >> 1;
  int idx = ((b >> 3) << 1) + (b & 1);      // 0..781
  int tid = threadIdx.x;
  int grp = tid >> 1, lane2 = tid & 1;
  int node = idx * 128 + grp;
  if (node >= N_NODES) return;
  int beg = rp[node], end = rp[node + 1];
  const u8* hp = h8 + (size_t)plane * (N_NODES * 32) + lane2 * 16;
  f32x2 av[8];
#pragma unroll
  for (int i = 0; i < 8; i++) av[i] = (f32x2){0.f, 0.f};
  int j = beg;
  for (; j + 8 <= end; j += 8) {
    int4 ci = *(const int4*)(col + j + lane2 * 4);   // lane0: j..j+3, lane1: j+4..j+7
    int cia[4] = {ci.x, ci.y, ci.z, ci.w};
    uint4 v[8];
#pragma unroll
    for (int e = 0; e < 8; e++) {
      int s = __shfl(cia[e & 3], e >> 2, 2);
      v[e] = *(const uint4*)(hp + ((size_t)(unsigned)s << 5));
    }
#pragma unroll
    for (int e = 0; e < 8; e++) {
      av[0] += __builtin_amdgcn_cvt_pk_f32_fp8(v[e].x, false);
      av[1] += __builtin_amdgcn_cvt_pk_f32_fp8(v[e].x, true);
      av[2] += __builtin_amdgcn_cvt_pk_f32_fp8(v[e].y, false);
      av[3] += __builtin_amdgcn_cvt_pk_f32_fp8(v[e].y, true);
      av[4] += __builtin_amdgcn_cvt_pk_f32_fp8(v[e].z, false);
      av[5] += __builtin_amdgcn_cvt_pk_f32_fp8(v[e].z, true);
      av[6] += __builtin_amdgcn_cvt_pk_f32_fp8(v[e].w, false);
      av[7] += __builtin_amdgcn_cvt_pk_f32_fp8(v[e].w, true);
    }
  }
  for (; j < end; j++) {
    int s = col[j];
    uint4 vv = *(const uint4*)(hp + ((size_t)(unsigned)s << 5));
    av[0] += __builtin_amdgcn_cvt_pk_f32_fp8(vv.x, false);
    av[1] += __builtin_amdgcn_cvt_pk_f32_fp8(vv.x, true);
    av[2] += __builtin_amdgcn_cvt_pk_f32_fp8(vv.y, false);
    av[3] += __builtin_amdgcn_cvt_pk_f32_fp8(vv.y, true);
    av[4] += __builtin_amdgcn_cvt_pk_f32_fp8(vv.z, false);
    av[5] += __builtin_amdgcn_cvt_pk_f32_fp8(vv.z, true);
    av[6] += __builtin_amdgcn_cvt_pk_f32_fp8(vv.w, false);
    av[7] += __builtin_amdgcn_cvt_pk_f32_fp8(vv.w, true);
  }
  float wd = invdeg[node];
  u16* mp = mean + (size_t)plane * (N_NODES * 32) + (size_t)node * 32 + lane2 * 16;
  *(ushort4*)(mp)      = make_ushort4(f2b(av[0][0]*wd), f2b(av[0][1]*wd), f2b(av[1][0]*wd), f2b(av[1][1]*wd));
  *(ushort4*)(mp + 4)  = make_ushort4(f2b(av[2][0]*wd), f2b(av[2][1]*wd), f2b(av[3][0]*wd), f2b(av[3][1]*wd));
  *(ushort4*)(mp + 8)  = make_ushort4(f2b(av[4][0]*wd), f2b(av[4][1]*wd), f2b(av[5][0]*wd), f2b(av[5][1]*wd));
  *(ushort4*)(mp + 12) = make_ushort4(f2b(av[6][0]*wd), f2b(av[6][1]*wd), f2b(av[7][0]*wd), f2b(av[7][1]*wd));
}

// ------- plane-major gather of gl (16ch bf16 = 32B rows): 2 lanes x 16B -------
__global__ __launch_bounds__(256) void out_gather16_k(
    const u16* __restrict__ gl, const int* __restrict__ rp,
    const int* __restrict__ col, const float* __restrict__ invdeg,
    float* __restrict__ partial) {
  int b = blockIdx.x;
  int plane = (b & 7) >> 1;
  int idx = ((b >> 3) << 1) + (b & 1);
  int tid = threadIdx.x;
  int grp = tid >> 1, lane2 = tid & 1;
  int node = idx * 128 + grp;
  if (node >= N_NODES) return;
  int beg = rp[node], end = rp[node + 1];
  const u16* gp = gl + (size_t)plane * (N_NODES * 16) + lane2 * 8;
  float a[8];
#pragma unroll
  for (int i = 0; i < 8; i++) a[i] = 0.f;
  int j = beg;
  for (; j + 8 <= end; j += 8) {
    int4 ci = *(const int4*)(col + j + lane2 * 4);
    int cia[4] = {ci.x, ci.y, ci.z, ci.w};
    uint4 v[8];
#pragma unroll
    for (int e = 0; e < 8; e++) {
      int s = __shfl(cia[e & 3], e >> 2, 2);
      v[e] = *(const uint4*)(gp + ((size_t)(unsigned)s << 4));
    }
#pragma unroll
    for (int e = 0; e < 8; e++) {
      a[0] += bfl(v[e].x); a[1] += bfh(v[e].x);
      a[2] += bfl(v[e].y); a[3] += bfh(v[e].y);
      a[4] += bfl(v[e].z); a[5] += bfh(v[e].z);
      a[6] += bfl(v[e].w); a[7] += bfh(v[e].w);
    }
  }
  for (; j < end; j++) {
    int s = col[j];
    uint4 vv = *(const uint4*)(gp + ((size_t)(unsigned)s << 4));
    a[0] += bfl(vv.x); a[1] += bfh(vv.x);
    a[2] += bfl(vv.y); a[3] += bfh(vv.y);
    a[4] += bfl(vv.z); a[5] += bfh(vv.z);
    a[6] += bfl(vv.w); a[7] += bfh(vv.w);
  }
  float wd = invdeg[node];
  float* pp = partial + (size_t)node * 64 + plane * 16 + lane2 * 8;
  *(float4*)(pp)     = make_float4(a[0]*wd, a[1]*wd, a[2]*wd, a[3]*wd);
  *(float4*)(pp + 4) = make_float4(a[4]*wd, a[5]*wd, a[6]*wd, a[7]*wd);
}

// ------- output softmax: out = log_softmax(partial + gr + blo), half-wave per node -------
__global__ __launch_bounds__(256) void out_softmax_k(
    const float* __restrict__ partial, const u16* __restrict__ gr,
    const float* __restrict__ blo, float* __restrict__ outp) {
  int node = blockIdx.x * 8 + (threadIdx.x >> 5);
  int lane = threadIdx.x & 31;
  if (node >= N_NODES) return;
  float2 pz = *(const float2*)(partial + (size_t)node * 64 + lane * 2);
  unsigned g = *(const unsigned*)(gr + (size_t)node * 64 + lane * 2);
  float z0 = pz.x + bfl(g) + blo[lane * 2];
  float z1 = pz.y + bfh(g) + blo[lane * 2 + 1];
  float mx = fmaxf(z0, z1);
#pragma unroll
  for (int off = 16; off >= 1; off >>= 1) mx = fmaxf(mx, __shfl_xor(mx, off, 32));
  float s = __expf(z0 - mx) + __expf(z1 - mx);
#pragma unroll
  for (int off = 16; off >= 1; off >>= 1) s += __shfl_xor(s, off, 32);
  float ro = mx + __logf(s);
  float2 o = make_float2(z0 - ro, z1 - ro);
  *(float2*)(outp + (size_t)node * 64 + lane * 2) = o;
}

// ------- inProj: z = x@WpT + bp; inp=bf16(z); h=bf16(relu(z)); h8=fp8(relu(z)) planes -------
__global__ __launch_bounds__(256) void inproj_mfma_k(
    const float* __restrict__ X, const u16* __restrict__ P,
    const float* __restrict__ bias,
    u16* __restrict__ inp, u16* __restrict__ hout, u8* __restrict__ h8out, int M) {
  __shared__ float zb[64 * 132];
  int tid = threadIdx.x;
  int w = tid >> 6, lane = tid & 63;
  int quad = lane >> 4, l15 = lane & 15;
  int m0 = blockIdx.x * 64;
  int rowa = m0 + w * 16 + l15; if (rowa > M - 1) rowa = M - 1;
  f32x4 acc[8] = {};
#pragma unroll
  for (int kt = 0; kt < 4; kt++) {
    const float* xr = X + (long)rowa * 128 + kt * 32 + quad * 8;
    float4 p0 = *(const float4*)xr;
    float4 p1 = *(const float4*)(xr + 4);
    union { ushort4 u4[2]; bf16x8 v; } fa;
    fa.u4[0] = make_ushort4(f2b(p0.x), f2b(p0.y), f2b(p0.z), f2b(p0.w));
    fa.u4[1] = make_ushort4(f2b(p1.x), f2b(p1.y), f2b(p1.z), f2b(p1.w));
    const u16* pb = P + ((kt * 8) * 64 + lane) * 8;
#pragma unroll
    for (int nt = 0; nt < 8; nt++) {
      bf16x8 bf = *(const bf16x8*)(pb + nt * 512);
      acc[nt] = __builtin_amdgcn_mfma_f32_16x16x32_bf16(fa.v, bf, acc[nt], 0, 0, 0);
    }
  }
#pragma unroll
  for (int nt = 0; nt < 8; nt++) {
    int c = nt * 16 + l15;
    float b = bias[c];
#pragma unroll
    for (int r = 0; r < 4; r++)
      zb[(w * 16 + quad * 4 + r) * 132 + c] = acc[nt][r] + b;
  }
  __syncthreads();
  int r = lane >> 2, seg = lane & 3;
  long grow = m0 + w * 16 + r;
  if (grow < M) {
    const float* zrow = &zb[(w * 16 + r) * 132 + seg * 32];
    u16* ip = inp + grow * 128 + seg * 32;
    u16* hp = hout + grow * 128 + seg * 32;
    u8*  qp = h8out + (size_t)seg * (N_NODES * 32) + grow * 32;
#pragma unroll
    for (int b = 0; b < 4; b++) {
      float zv[8];
      *(float4*)&zv[0] = *(const float4*)(zrow + b * 8);
      *(float4*)&zv[4] = *(const float4*)(zrow + b * 8 + 4);
      float rv[8];
#pragma unroll
      for (int jj = 0; jj < 8; jj++) rv[jj] = fmaxf(zv[jj], 0.f);
      *(ushort4*)(ip + b * 8)     = make_ushort4(f2b(zv[0]), f2b(zv[1]), f2b(zv[2]), f2b(zv[3]));
      *(ushort4*)(ip + b * 8 + 4) = make_ushort4(f2b(zv[4]), f2b(zv[5]), f2b(zv[6]), f2b(zv[7]));
      *(ushort4*)(hp + b * 8)     = make_ushort4(f2b(rv[0]), f2b(rv[1]), f2b(rv[2]), f2b(rv[3]));
      *(ushort4*)(hp + b * 8 + 4) = make_ushort4(f2b(rv[4]), f2b(rv[5]), f2b(rv[6]), f2b(rv[7]));
      unsigned q0 = 0, q1 = 0;
      q0 = __builtin_amdgcn_cvt_pk_fp8_f32(rv[0], rv[1], q0, false);
      q0 = __builtin_amdgcn_cvt_pk_fp8_f32(rv[2], rv[3], q0, true);
      q1 = __builtin_amdgcn_cvt_pk_fp8_f32(rv[4], rv[5], q1, false);
      q1 = __builtin_amdgcn_cvt_pk_fp8_f32(rv[6], rv[7], q1, true);
      *(uint2*)(qp + b * 8) = make_uint2(q0, q1);
    }
  }
}

// ------- SAGE layer: h = bf16(relu(mean@Wl + bl + h@Wr) + 0.2*inp), in-place;
//         mean input is PLANE-major; fp8 copy emitted in PLANE-major (h8out may be null) -------
__global__ __launch_bounds__(256) void sage_mfma8_k(
    const u16* __restrict__ A0, const u16* __restrict__ P0,
    const u16* __restrict__ A1, const u16* __restrict__ P1,
    const float* __restrict__ bias, const u16* __restrict__ inp,
    u16* __restrict__ outp, u8* __restrict__ h8out, int M) {
  __shared__ float zb[64 * 132];
  int tid = threadIdx.x;
  int w = tid >> 6, lane = tid & 63;
  int quad = lane >> 4, l15 = lane & 15;
  int m0 = blockIdx.x * 64;
  int rowa = m0 + w * 16 + l15; if (rowa > M - 1) rowa = M - 1;
  f32x4 acc[8] = {};
#pragma unroll
  for (int kt = 0; kt < 4; kt++) {
    bf16x8 am = *(const bf16x8*)(A0 + (size_t)kt * (N_NODES * 32) + (size_t)rowa * 32 + quad * 8);
    bf16x8 ar = *(const bf16x8*)(A1 + (long)rowa * 128 + kt * 32 + quad * 8);
    const u16* pl = P0 + ((kt * 8) * 64 + lane) * 8;
    const u16* pr = P1 + ((kt * 8) * 64 + lane) * 8;
#pragma unroll
    for (int nt = 0; nt < 8; nt++) {
      bf16x8 b0 = *(const bf16x8*)(pl + nt * 512);
      bf16x8 b1 = *(const bf16x8*)(pr + nt * 512);
      acc[nt] = __builtin_amdgcn_mfma_f32_16x16x32_bf16(am, b0, acc[nt], 0, 0, 0);
      acc[nt] = __builtin_amdgcn_mfma_f32_16x16x32_bf16(ar, b1, acc[nt], 0, 0, 0);
    }
  }
#pragma unroll
  for (int nt = 0; nt < 8; nt++) {
    int c = nt * 16 + l15;
    float b = bias[c];
#pragma unroll
    for (int r = 0; r < 4; r++)
      zb[(w * 16 + quad * 4 + r) * 132 + c] = fmaxf(acc[nt][r] + b, 0.f);
  }
  __syncthreads();
  int r = lane >> 2, seg = lane & 3;
  long grow = m0 + w * 16 + r;
  if (grow < M) {
    const float* zrow = &zb[(w * 16 + r) * 132 + seg * 32];
    const u16* ip = inp + grow * 128 + seg * 32;
    u16* op = outp + grow * 128 + seg * 32;
#pragma unroll
    for (int b = 0; b < 4; b++) {
      float zv[8];
      *(float4*)&zv[0] = *(const float4*)(zrow + b * 8);
      *(float4*)&zv[4] = *(const float4*)(zrow + b * 8 + 4);
      uint2 iv0 = *(const uint2*)(ip + b * 8);
      uint2 iv1 = *(const uint2*)(ip + b * 8 + 4);
      float fv[8];
      fv[0] = zv[0] + 0.2f * bfl(iv0.x); fv[1] = zv[1] + 0.2f * bfh(iv0.x);
      fv[2] = zv[2] + 0.2f * bfl(iv0.y); fv[3] = zv[3] + 0.2f * bfh(iv0.y);
      fv[4] = zv[4] + 0.2f * bfl(iv1.x); fv[5] = zv[5] + 0.2f * bfh(iv1.x);
      fv[6] = zv[6] + 0.2f * bfl(iv1.y); fv[7] = zv[7] + 0.2f * bfh(iv1.y);
      *(ushort4*)(op + b * 8)     = make_ushort4(f2b(fv[0]), f2b(fv[1]), f2b(fv[2]), f2b(fv[3]));
      *(ushort4*)(op + b * 8 + 4) = make_ushort4(f2b(fv[4]), f2b(fv[5]), f2b(fv[6]), f2b(fv[7]));
      if (h8out) {
        unsigned q0 = 0, q1 = 0;
        q0 = __builtin_amdgcn_cvt_pk_fp8_f32(fv[0], fv[1], q0, false);
        q0 = __builtin_amdgcn_cvt_pk_fp8_f32(fv[2], fv[3], q0, true);
        q1 = __builtin_amdgcn_cvt_pk_fp8_f32(fv[4], fv[5], q1, false);
        q1 = __builtin_amdgcn_cvt_pk_fp8_f32(fv[6], fv[7], q1, true);
        *(uint2*)(h8out + (size_t)seg * (N_NODES * 32) + grow * 32 + b * 8) = make_uint2(q0, q1);
      }
    }
  }
}

// ------- output projection: gl = h@WloT (PLANE-major), gr = h@WroT (row-major) -------
__global__ __launch_bounds__(256) void out_proj_k(
    const u16* __restrict__ A, const u16* __restrict__ PLO,
    const u16* __restrict__ PRO, u16* __restrict__ gl, u16* __restrict__ gr, int M) {
  __shared__ float zb[64 * 132];
  int tid = threadIdx.x;
  int w = tid >> 6, lane = tid & 63;
  int quad = lane >> 4, l15 = lane & 15;
  int m0 = blockIdx.x * 64;
  int rowa = m0 + w * 16 + l15; if (rowa > M - 1) rowa = M - 1;
  f32x4 acc[8] = {};
#pragma unroll
  for (int kt = 0; kt < 4; kt++) {
    bf16x8 af = *(const bf16x8*)(A + (long)rowa * 128 + kt * 32 + quad * 8);
#pragma unroll
    for (int nt = 0; nt < 4; nt++) {
      bf16x8 b0 = *(const bf16x8*)(PLO + ((kt * 4 + nt) * 64 + lane) * 8);
      bf16x8 b1 = *(const bf16x8*)(PRO + ((kt * 4 + nt) * 64 + lane) * 8);
      acc[nt]     = __builtin_amdgcn_mfma_f32_16x16x32_bf16(af, b0, acc[nt], 0, 0, 0);
      acc[4 + nt] = __builtin_amdgcn_mfma_f32_16x16x32_bf16(af, b1, acc[4 + nt], 0, 0, 0);
    }
  }
  // zb cols 0-63 = gl, 64-127 = gr
#pragma unroll
  for (int nt = 0; nt < 4; nt++) {
    int c = nt * 16 + l15;
#pragma unroll
    for (int r = 0; r < 4; r++) {
      zb[(w * 16 + quad * 4 + r) * 132 + c]      = acc[nt][r];
      zb[(w * 16 + quad * 4 + r) * 132 + 64 + c] = acc[4 + nt][r];
    }
  }
  __syncthreads();
  int r = lane >> 2, seg = lane & 3;
  long grow = m0 + w * 16 + r;
  if (grow < M) {
    const float* zrow = &zb[(w * 16 + r) * 132 + seg * 32];
#pragma unroll
    for (int b = 0; b < 4; b++) {
      float zv[8];
      *(float4*)&zv[0] = *(const float4*)(zrow + b * 8);
      *(float4*)&zv[4] = *(const float4*)(zrow + b * 8 + 4);
      u16* dp;
      if (seg < 2) {
        int plane = seg * 2 + (b >> 1);
        dp = gl + (size_t)plane * (N_NODES * 16) + grow * 16 + (b & 1) * 8;
      } else {
        dp = gr + grow * 64 + (seg - 2) * 32 + b * 8;
      }
      *(ushort4*)(dp)     = make_ushort4(f2b(zv[0]), f2b(zv[1]), f2b(zv[2]), f2b(zv[3]));
      *(ushort4*)(dp + 4) = make_ushort4(f2b(zv[4]), f2b(zv[5]), f2b(zv[6]), f2b(zv[7]));
    }
  }
}

extern "C" void kernel_launch(void* const* d_in, const int* in_sizes, int n_in,
                              void* d_out, int out_size, void* d_ws, size_t ws_size,
                              hipStream_t stream) {
  if (ws_size < (size_t)WS_NEEDED) return;
  const float* x   = (const float*)d_in[0];
  const int*   ei  = (const int*)d_in[1];
  const float* Wp  = (const float*)d_in[2];
  const float* bp  = (const float*)d_in[3];
  const float* Wl  = (const float*)d_in[4];
  const float* bl  = (const float*)d_in[5];
  const float* Wr  = (const float*)d_in[6];
  const float* Wlo = (const float*)d_in[7];
  const float* blo = (const float*)d_in[8];
  const float* Wro = (const float*)d_in[9];
  float* out = (float*)d_out;
  char* ws = (char*)d_ws;
  int*   rp     = (int*)(ws + OFF_RP);
  float* invdeg = (float*)(ws + OFF_INVDEG);
  int*   bhist  = (int*)(ws + OFF_BHIST);
  int*   bbase  = (int*)(ws + OFF_BBASE);
  int*   deg    = (int*)(ws + OFF_DEG);
  int*   cur    = (int*)(ws + OFF_CUR);
  int*   col    = (int*)(ws + OFF_COL);
  u16*   pack   = (u16*)(ws + OFF_PACK);
  u16*   inp    = (u16*)(ws + OFF_INP);
  u16*   h      = (u16*)(ws + OFF_H);
  u8*    h8a    = (u8*)(ws + OFF_H8A);
  u8*    h8b    = (u8*)(ws + OFF_H8B);
  u16*   gl     = (u16*)(ws + OFF_GL);
  u16*   gr     = (u16*)(ws + OFF_GR);
  u16*   mean   = (u16*)(ws + OFF_MEAN);
  float* partial = (float*)(ws + OFF_MEAN);   // reused after last sage
  const int* srcv = ei;
  const int* dstv = ei + N_EDGES;

  // zero bhist/bbase (+pad) and deg table (cur initialized by scan2_k)
  hipMemsetAsync(ws + OFF_BHIST, 0, OFF_DEG - OFF_BHIST, stream);
  hipMemsetAsync(ws + OFF_DEG, 0, 400016u, stream);
  pack_weights_k<<<64, 256, 0, stream>>>(Wp, Wl, Wr, Wlo, Wro, pack);
  deg_k<<<EBLK, 256, 0, stream>>>(dstv, deg);
  scan1_k<<<NBUK, 256, 0, stream>>>(deg, rp, bhist);
  bscan_k<<<1, 512, 0, stream>>>(bhist, bbase, rp);
  scan2_k<<<NBUK, 256, 0, stream>>>(bbase, deg, rp, cur, invdeg);
  scatter_k<<<EBLK, 256, 0, stream>>>(srcv, dstv, cur, col);

  int gblk = (N_NODES + 63) / 64;
  int fblk = (N_NODES + 7) / 8;

  inproj_mfma_k<<<gblk, 256, 0, stream>>>(x, pack + PK_WP, bp, inp, h, h8a, N_NODES);

  aggregate_plane16_k<<<PBLK16, 256, 0, stream>>>(h8a, rp, col, invdeg, mean);
  sage_mfma8_k<<<gblk, 256, 0, stream>>>(mean, pack + PK_WL, h, pack + PK_WR,
                                         bl, inp, h, h8b, N_NODES);
  aggregate_plane16_k<<<PBLK16, 256, 0, stream>>>(h8b, rp, col, invdeg, mean);
  sage_mfma8_k<<<gblk, 256, 0, stream>>>(mean, pack + PK_WL + 16384, h, pack + PK_WR + 16384,
                                         bl + 128, inp, h, h8a, N_NODES);
  aggregate_plane16_k<<<PBLK16, 256, 0, stream>>>(h8a, rp, col, invdeg, mean);
  sage_mfma8_k<<<gblk, 256, 0, stream>>>(mean, pack + PK_WL + 32768, h, pack + PK_WR + 32768,
                                         bl + 256, inp, h, (u8*)nullptr, N_NODES);

  out_proj_k<<<gblk, 256, 0, stream>>>(h, pack + PK_WLO, pack + PK_WRO, gl, gr, N_NODES);
  out_gather16_k<<<PBLK16, 256, 0, stream>>>(gl, rp, col, invdeg, partial);
  out_softmax_k<<<fblk, 256, 0, stream>>>(partial, gr, blo, out);
}

// Round 14
// 542.623 us; speedup vs baseline: 1.2218x; 1.2218x over previous
//
#include <hip/hip_runtime.h>
#include <math.h>

#define N_NODES 100000
#define N_EDGES 1600000
#define NBUK 391          // ceil(N/256) buckets of 256 consecutive dst nodes
#define PCHUNK 8192       // edges per partition block
#define NPBLK 196         // ceil(E/PCHUNK)
#define PBLK16 3128       // 8 XCD-slots: 4 planes x 782 chunks of 128 nodes (out_gather)

typedef unsigned short u16;
typedef unsigned char u8;
typedef __bf16 bf16x8 __attribute__((ext_vector_type(8)));
typedef float f32x4 __attribute__((ext_vector_type(4)));
typedef float f32x2 __attribute__((ext_vector_type(2)));

// ---- workspace layout (bytes), 16B-aligned ----  (R10 proven layout)
#define OFF_RP      0u          // int[N+1]
#define OFF_INVDEG  400016u     // float[N]
#define OFF_BHIST   800016u     // int[392]
#define OFF_BBASE   801600u     // int[392]
#define OFF_GCUR    803200u     // int[391]
#define OFF_PCTR    804800u     // int[64] (unused, layout stability)
#define OFF_PAIRS   805056u     // uint2[E] = 12.8 MB
#define OFF_COL     13605056u   // int[E]
#define OFF_PACK    20005056u   // u16[131072] packed bf16 weight fragments
#define OFF_INP     20267200u   // u16[N*128] residual (pre-relu inProj), bf16
#define OFF_H       45867200u   // u16[N*128] h (in-place across layers), bf16, row-major
#define OFF_H8A     71467200u   // u8[N][128] fp8 copy of h, ROW-major, buffer A
#define OFF_H8B     84267200u   // u8[N][128] fp8 copy, ROW-major, buffer B
#define OFF_GL      97067200u   // u16[4][N][16] projected neighbor logits, PLANE-major bf16
#define OFF_GR      109867200u  // u16[N*64] projected root logits, bf16, row-major
#define OFF_MEAN    122667200u  // float[N][64] partial for output stage
#define WS_NEEDED   148267200u

// packed-weight element offsets (u16 units)
#define PK_WP   0
#define PK_WL   16384
#define PK_WR   65536
#define PK_WLO  114688
#define PK_WRO  122880

__device__ __forceinline__ float bfl(unsigned u) {
  union { unsigned i; float f; } v; v.i = u << 16; return v.f;
}
__device__ __forceinline__ float bfh(unsigned u) {
  union { unsigned i; float f; } v; v.i = u & 0xFFFF0000u; return v.f;
}
__device__ __forceinline__ u16 f2b(float f) {       // RTNE
  union { float f; unsigned i; } v; v.f = f;
  unsigned r = (v.i + 0x7FFFu + ((v.i >> 16) & 1u)) >> 16;
  return (u16)r;
}

// ---------------- pack fp32 weights -> bf16 MFMA B-fragments ----------------
__global__ __launch_bounds__(256) void pack_weights_k(
    const float* __restrict__ Wp, const float* __restrict__ Wl,
    const float* __restrict__ Wr, const float* __restrict__ Wlo,
    const float* __restrict__ Wro, u16* __restrict__ P) {
  int t = blockIdx.x * 256 + threadIdx.x;
  if (t >= 16384) return;
  const float* W; u16* dst; int j; int NT;
  if (t < 2048)        { W = Wp;                    dst = P + PK_WP;                j = t;                 NT = 8; }
  else if (t < 8192)   { int m = (t - 2048) >> 11;  j = (t - 2048) & 2047;
                         W = Wl + (m << 14);        dst = P + PK_WL + (m << 14);    NT = 8; }
  else if (t < 14336)  { int m = (t - 8192) >> 11;  j = (t - 8192) & 2047;
                         W = Wr + (m << 14);        dst = P + PK_WR + (m << 14);    NT = 8; }
  else if (t < 15360)  { j = t - 14336;             W = Wlo;  dst = P + PK_WLO;     NT = 4; }
  else                 { j = t - 15360;             W = Wro;  dst = P + PK_WRO;     NT = 4; }
  int lane = j & 63;
  int nt, kt;
  if (NT == 8) { nt = (j >> 6) & 7; kt = j >> 9; }
  else         { nt = (j >> 6) & 3; kt = j >> 8; }
  int n  = nt * 16 + (lane & 15);
  int k0 = kt * 32 + ((lane >> 4) << 3);
  const float* s = W + n * 128 + k0;
  ushort4 lo = make_ushort4(f2b(s[0]), f2b(s[1]), f2b(s[2]), f2b(s[3]));
  ushort4 hi = make_ushort4(f2b(s[4]), f2b(s[5]), f2b(s[6]), f2b(s[7]));
  *(ushort4*)(dst + j * 8)     = lo;
  *(ushort4*)(dst + j * 8 + 4) = hi;
}

// ---------- bucket histogram ----------
__global__ __launch_bounds__(256) void bhist_k(const int* __restrict__ dst,
                                               int* __restrict__ bhist) {
  __shared__ int lc[NBUK];
  int t = threadIdx.x;
  for (int i = t; i < NBUK; i += 256) lc[i] = 0;
  __syncthreads();
  int base = blockIdx.x * 4096;
#pragma unroll
  for (int r = 0; r < 16; r++) {
    int i = base + r * 256 + t;
    if (i < N_EDGES) atomicAdd(&lc[dst[i] >> 8], 1);
  }
  __syncthreads();
  for (int i = t; i < NBUK; i += 256)
    if (lc[i]) atomicAdd(&bhist[i], lc[i]);
}

// ---------- single-block scan of bucket counts ----------
__global__ __launch_bounds__(512) void bscan_k(const int* __restrict__ bhist,
                                               int* __restrict__ bbase,
                                               int* __restrict__ gcur,
                                               int* __restrict__ rp) {
  __shared__ int s[512];
  int t = threadIdx.x;
  int v = (t < NBUK) ? bhist[t] : 0;
  s[t] = v;
  __syncthreads();
  for (int off = 1; off < 512; off <<= 1) {
    int u = (t >= off) ? s[t - off] : 0;
    __syncthreads();
    s[t] += u;
    __syncthreads();
  }
  if (t < NBUK) { int e = s[t] - v; bbase[t] = e; gcur[t] = e; }
  if (t == NBUK - 1) { bbase[NBUK] = s[t]; rp[N_NODES] = s[t]; }
}

// ---------- partition edges into bucket-contiguous (src,dst) pairs ----------
__global__ __launch_bounds__(256) void part_k(const int* __restrict__ src,
                                              const int* __restrict__ dst,
                                              int* __restrict__ gcur,
                                              uint2* __restrict__ pairs) {
  __shared__ int lcnt[NBUK + 1];
  __shared__ int lofs[512];
  __shared__ int cur[NBUK];
  __shared__ int gslot[NBUK];
  __shared__ uint2 stag[PCHUNK];
  int t = threadIdx.x;
  for (int i = t; i < NBUK + 1; i += 256) lcnt[i] = 0;
  __syncthreads();
  int base = blockIdx.x * PCHUNK;
#pragma unroll
  for (int r = 0; r < PCHUNK / 256; r++) {
    int i = base + r * 256 + t;
    if (i < N_EDGES) atomicAdd(&lcnt[dst[i] >> 8], 1);
  }
  __syncthreads();
  {
    int e1 = t + 256;
    lofs[t]  = (t  <= NBUK) ? lcnt[t]  : 0;
    lofs[e1] = (e1 <= NBUK) ? lcnt[e1] : 0;
    __syncthreads();
    for (int off = 1; off < 512; off <<= 1) {
      int a0 = (t  >= off) ? lofs[t  - off] : 0;
      int a1 = (e1 >= off) ? lofs[e1 - off] : 0;
      __syncthreads();
      lofs[t] += a0; lofs[e1] += a1;
      __syncthreads();
    }
    int o0 = lofs[t]  - ((t  <= NBUK) ? lcnt[t]  : 0);
    int o1 = lofs[e1] - ((e1 <= NBUK) ? lcnt[e1] : 0);
    __syncthreads();
    lofs[t] = o0; lofs[e1] = o1;
    __syncthreads();
  }
  for (int i = t; i < NBUK; i += 256) cur[i] = lofs[i];
  __syncthreads();
#pragma unroll
  for (int r = 0; r < PCHUNK / 256; r++) {
    int i = base + r * 256 + t;
    if (i < N_EDGES) {
      int d = dst[i];
      int slot = atomicAdd(&cur[d >> 8], 1);
      stag[slot] = make_uint2((unsigned)src[i], (unsigned)d);
    }
  }
  __syncthreads();
  for (int i = t; i < NBUK; i += 256)
    if (lcnt[i]) gslot[i] = atomicAdd(&gcur[i], lcnt[i]);
  __syncthreads();
  int total = lofs[NBUK];
  for (int p = t; p < total; p += 256) {
    uint2 pr = stag[p];
    int b = (int)(pr.y >> 8);
    pairs[gslot[b] + (p - lofs[b])] = pr;
  }
}

// ---------- per-bucket CSR finalize ----------
__global__ __launch_bounds__(256) void csr_k(const uint2* __restrict__ pairs,
                                             const int* __restrict__ bbase,
                                             int* __restrict__ rp,
                                             float* __restrict__ invdeg,
                                             int* __restrict__ col) {
  __shared__ int cnt[256];
  __shared__ int scn[256];
  __shared__ int cur[256];
  int b = blockIdx.x, t = threadIdx.x;
  int lo = bbase[b], hi = bbase[b + 1];
  cnt[t] = 0;
  __syncthreads();
  for (int p = lo + t; p < hi; p += 256)
    atomicAdd(&cnt[pairs[p].y & 255], 1);
  __syncthreads();
  int c = cnt[t];
  scn[t] = c;
  __syncthreads();
  for (int off = 1; off < 256; off <<= 1) {
    int v = (t >= off) ? scn[t - off] : 0;
    __syncthreads();
    scn[t] += v;
    __syncthreads();
  }
  int excl = scn[t] - c;
  int node = (b << 8) + t;
  if (node < N_NODES) {
    rp[node] = lo + excl;
    invdeg[node] = 1.0f / (float)(c > 1 ? c : 1);
  }
  cur[t] = lo + excl;
  __syncthreads();
  for (int p = lo + t; p < hi; p += 256) {
    uint2 pr = pairs[p];
    int slot = atomicAdd(&cur[pr.y & 255], 1);
    col[slot] = (int)pr.x;
  }
}

// ------- FUSED SAGE: gather-mean (phase 1, LDS) + MFMA + epilogue (one block = 64 nodes)
// Rationale (R13 post-mortem): aggregate (fabric-request-bound, VALU idle) and sage
// (VALU/latency-bound, fabric idle) ran serially at 53+50 us/layer. Fused, the 4
// resident blocks/CU overlap gather-phase and MFMA-phase across blocks -> ~max of the
// two demands. mean lives in LDS (bf16 [64][136]) overlaying zb; extra barrier before
// zb overwrite. h8 is ROW-major (full 128B rows needed per node).
__global__ __launch_bounds__(256) void sage_fused_k(
    const u8* __restrict__ h8, const int* __restrict__ rp,
    const int* __restrict__ col, const float* __restrict__ invdeg,
    const u16* __restrict__ P0, const u16* __restrict__ A1,
    const u16* __restrict__ P1, const float* __restrict__ bias,
    const u16* __restrict__ inp, u16* __restrict__ outp,
    u8* __restrict__ h8out, int M) {
  __shared__ float zb[64 * 132];          // 33792 B
  u16* meanl = (u16*)zb;                  // [64][136] bf16 overlay (17408 B), freed pre-zb
  int tid = threadIdx.x;
  int m0 = blockIdx.x * 64;
  // ---- phase 1: gather mean for this block's 64 nodes into LDS ----
  {
    int grp = tid >> 3, lane8 = tid & 7;  // 8 lanes x 16B = full 128B fp8 row
    const u8* hp = h8 + lane8 * 16;
#pragma unroll
    for (int half = 0; half < 2; half++) {
      int lrow = half * 32 + grp;
      int node = m0 + lrow; if (node > M - 1) node = M - 1;
      int beg = rp[node], end = rp[node + 1];
      float a[16];
#pragma unroll
      for (int i = 0; i < 16; i++) a[i] = 0.f;
      for (int j = beg; j < end; j += 8) {
        int ci = 0;
        if (j + lane8 < end) ci = col[j + lane8];
        int cnt = end - j;
#pragma unroll
        for (int e = 0; e < 8; e++) {
          if (e < cnt) {
            int s = __shfl(ci, e, 8);
            uint4 v = *(const uint4*)(hp + (size_t)(unsigned)s * 128);
            f32x2 p0 = __builtin_amdgcn_cvt_pk_f32_fp8(v.x, false);
            f32x2 p1 = __builtin_amdgcn_cvt_pk_f32_fp8(v.x, true);
            f32x2 p2 = __builtin_amdgcn_cvt_pk_f32_fp8(v.y, false);
            f32x2 p3 = __builtin_amdgcn_cvt_pk_f32_fp8(v.y, true);
            f32x2 p4 = __builtin_amdgcn_cvt_pk_f32_fp8(v.z, false);
            f32x2 p5 = __builtin_amdgcn_cvt_pk_f32_fp8(v.z, true);
            f32x2 p6 = __builtin_amdgcn_cvt_pk_f32_fp8(v.w, false);
            f32x2 p7 = __builtin_amdgcn_cvt_pk_f32_fp8(v.w, true);
            a[0]  += p0[0]; a[1]  += p0[1]; a[2]  += p1[0]; a[3]  += p1[1];
            a[4]  += p2[0]; a[5]  += p2[1]; a[6]  += p3[0]; a[7]  += p3[1];
            a[8]  += p4[0]; a[9]  += p4[1]; a[10] += p5[0]; a[11] += p5[1];
            a[12] += p6[0]; a[13] += p6[1]; a[14] += p7[0]; a[15] += p7[1];
          }
        }
      }
      float wd = invdeg[node];
      u16* mp = meanl + lrow * 136 + lane8 * 16;
      *(ushort4*)(mp)      = make_ushort4(f2b(a[0]*wd),  f2b(a[1]*wd),  f2b(a[2]*wd),  f2b(a[3]*wd));
      *(ushort4*)(mp + 4)  = make_ushort4(f2b(a[4]*wd),  f2b(a[5]*wd),  f2b(a[6]*wd),  f2b(a[7]*wd));
      *(ushort4*)(mp + 8)  = make_ushort4(f2b(a[8]*wd),  f2b(a[9]*wd),  f2b(a[10]*wd), f2b(a[11]*wd));
      *(ushort4*)(mp + 12) = make_ushort4(f2b(a[12]*wd), f2b(a[13]*wd), f2b(a[14]*wd), f2b(a[15]*wd));
    }
  }
  __syncthreads();
  // ---- phase 2: MFMA, mean from LDS ----
  int w = tid >> 6, lane = tid & 63;
  int quad = lane >> 4, l15 = lane & 15;
  int rowa = m0 + w * 16 + l15; if (rowa > M - 1) rowa = M - 1;
  int lrowa = w * 16 + l15;
  f32x4 acc[8] = {};
#pragma unroll
  for (int kt = 0; kt < 4; kt++) {
    bf16x8 am = *(const bf16x8*)(meanl + lrowa * 136 + kt * 32 + quad * 8);
    bf16x8 ar = *(const bf16x8*)(A1 + (long)rowa * 128 + kt * 32 + quad * 8);
    const u16* pl = P0 + ((kt * 8) * 64 + lane) * 8;
    const u16* pr = P1 + ((kt * 8) * 64 + lane) * 8;
#pragma unroll
    for (int nt = 0; nt < 8; nt++) {
      bf16x8 b0 = *(const bf16x8*)(pl + nt * 512);
      bf16x8 b1 = *(const bf16x8*)(pr + nt * 512);
      acc[nt] = __builtin_amdgcn_mfma_f32_16x16x32_bf16(am, b0, acc[nt], 0, 0, 0);
      acc[nt] = __builtin_amdgcn_mfma_f32_16x16x32_bf16(ar, b1, acc[nt], 0, 0, 0);
    }
  }
  __syncthreads();   // all mean reads complete before zb overwrites the overlay
#pragma unroll
  for (int nt = 0; nt < 8; nt++) {
    int c = nt * 16 + l15;
    float b = bias[c];
#pragma unroll
    for (int r = 0; r < 4; r++)
      zb[(w * 16 + quad * 4 + r) * 132 + c] = fmaxf(acc[nt][r] + b, 0.f);
  }
  __syncthreads();
  int r = lane >> 2, seg = lane & 3;
  long grow = m0 + w * 16 + r;
  if (grow < M) {
    const float* zrow = &zb[(w * 16 + r) * 132 + seg * 32];
    const u16* ip = inp + grow * 128 + seg * 32;
    u16* op = outp + grow * 128 + seg * 32;
#pragma unroll
    for (int b = 0; b < 4; b++) {
      float zv[8];
      *(float4*)&zv[0] = *(const float4*)(zrow + b * 8);
      *(float4*)&zv[4] = *(const float4*)(zrow + b * 8 + 4);
      uint2 iv0 = *(const uint2*)(ip + b * 8);
      uint2 iv1 = *(const uint2*)(ip + b * 8 + 4);
      float fv[8];
      fv[0] = zv[0] + 0.2f * bfl(iv0.x); fv[1] = zv[1] + 0.2f * bfh(iv0.x);
      fv[2] = zv[2] + 0.2f * bfl(iv0.y); fv[3] = zv[3] + 0.2f * bfh(iv0.y);
      fv[4] = zv[4] + 0.2f * bfl(iv1.x); fv[5] = zv[5] + 0.2f * bfh(iv1.x);
      fv[6] = zv[6] + 0.2f * bfl(iv1.y); fv[7] = zv[7] + 0.2f * bfh(iv1.y);
      *(ushort4*)(op + b * 8)     = make_ushort4(f2b(fv[0]), f2b(fv[1]), f2b(fv[2]), f2b(fv[3]));
      *(ushort4*)(op + b * 8 + 4) = make_ushort4(f2b(fv[4]), f2b(fv[5]), f2b(fv[6]), f2b(fv[7]));
      if (h8out) {
        unsigned q0 = 0, q1 = 0;
        q0 = __builtin_amdgcn_cvt_pk_fp8_f32(fv[0], fv[1], q0, false);
        q0 = __builtin_amdgcn_cvt_pk_fp8_f32(fv[2], fv[3], q0, true);
        q1 = __builtin_amdgcn_cvt_pk_fp8_f32(fv[4], fv[5], q1, false);
        q1 = __builtin_amdgcn_cvt_pk_fp8_f32(fv[6], fv[7], q1, true);
        *(uint2*)(h8out + grow * 128 + seg * 32 + b * 8) = make_uint2(q0, q1);
      }
    }
  }
}

// ------- plane-major gather of gl (16ch bf16 = 32B rows): 2 lanes x 16B -------
__global__ __launch_bounds__(256) void out_gather16_k(
    const u16* __restrict__ gl, const int* __restrict__ rp,
    const int* __restrict__ col, const float* __restrict__ invdeg,
    float* __restrict__ partial) {
  int b = blockIdx.x;
  int plane = (b & 7) >> 1;
  int idx = ((b >> 3) << 1) + (b & 1);
  int tid = threadIdx.x;
  int grp = tid >> 1, lane2 = tid & 1;
  int node = idx * 128 + grp;
  if (node >= N_NODES) return;
  int beg = rp[node], end = rp[node + 1];
  const u16* gp = gl + (size_t)plane * (N_NODES * 16) + lane2 * 8;
  float a[8];
#pragma unroll
  for (int i = 0; i < 8; i++) a[i] = 0.f;
  int j = beg;
  for (; j + 8 <= end; j += 8) {
    int4 ci = *(const int4*)(col + j + lane2 * 4);
    int cia[4] = {ci.x, ci.y, ci.z, ci.w};
    uint4 v[8];
#pragma unroll
    for (int e = 0; e < 8; e++) {
      int s = __shfl(cia[e & 3], e >> 2, 2);
      v[e] = *(const uint4*)(gp + ((size_t)(unsigned)s << 4));
    }
#pragma unroll
    for (int e = 0; e < 8; e++) {
      a[0] += bfl(v[e].x); a[1] += bfh(v[e].x);
      a[2] += bfl(v[e].y); a[3] += bfh(v[e].y);
      a[4] += bfl(v[e].z); a[5] += bfh(v[e].z);
      a[6] += bfl(v[e].w); a[7] += bfh(v[e].w);
    }
  }
  for (; j < end; j++) {
    int s = col[j];
    uint4 vv = *(const uint4*)(gp + ((size_t)(unsigned)s << 4));
    a[0] += bfl(vv.x); a[1] += bfh(vv.x);
    a[2] += bfl(vv.y); a[3] += bfh(vv.y);
    a[4] += bfl(vv.z); a[5] += bfh(vv.z);
    a[6] += bfl(vv.w); a[7] += bfh(vv.w);
  }
  float wd = invdeg[node];
  float* pp = partial + (size_t)node * 64 + plane * 16 + lane2 * 8;
  *(float4*)(pp)     = make_float4(a[0]*wd, a[1]*wd, a[2]*wd, a[3]*wd);
  *(float4*)(pp + 4) = make_float4(a[4]*wd, a[5]*wd, a[6]*wd, a[7]*wd);
}

// ------- output softmax: out = log_softmax(partial + gr + blo), half-wave per node -------
__global__ __launch_bounds__(256) void out_softmax_k(
    const float* __restrict__ partial, const u16* __restrict__ gr,
    const float* __restrict__ blo, float* __restrict__ outp) {
  int node = blockIdx.x * 8 + (threadIdx.x >> 5);
  int lane = threadIdx.x & 31;
  if (node >= N_NODES) return;
  float2 pz = *(const float2*)(partial + (size_t)node * 64 + lane * 2);
  unsigned g = *(const unsigned*)(gr + (size_t)node * 64 + lane * 2);
  float z0 = pz.x + bfl(g) + blo[lane * 2];
  float z1 = pz.y + bfh(g) + blo[lane * 2 + 1];
  float mx = fmaxf(z0, z1);
#pragma unroll
  for (int off = 16; off >= 1; off >>= 1) mx = fmaxf(mx, __shfl_xor(mx, off, 32));
  float s = __expf(z0 - mx) + __expf(z1 - mx);
#pragma unroll
  for (int off = 16; off >= 1; off >>= 1) s += __shfl_xor(s, off, 32);
  float ro = mx + __logf(s);
  float2 o = make_float2(z0 - ro, z1 - ro);
  *(float2*)(outp + (size_t)node * 64 + lane * 2) = o;
}

// ------- inProj: z = x@WpT + bp; inp=bf16(z); h=bf16(relu(z)); h8=fp8(relu(z)) ROW-major -------
__global__ __launch_bounds__(256) void inproj_mfma_k(
    const float* __restrict__ X, const u16* __restrict__ P,
    const float* __restrict__ bias,
    u16* __restrict__ inp, u16* __restrict__ hout, u8* __restrict__ h8out, int M) {
  __shared__ float zb[64 * 132];
  int tid = threadIdx.x;
  int w = tid >> 6, lane = tid & 63;
  int quad = lane >> 4, l15 = lane & 15;
  int m0 = blockIdx.x * 64;
  int rowa = m0 + w * 16 + l15; if (rowa > M - 1) rowa = M - 1;
  f32x4 acc[8] = {};
#pragma unroll
  for (int kt = 0; kt < 4; kt++) {
    const float* xr = X + (long)rowa * 128 + kt * 32 + quad * 8;
    float4 p0 = *(const float4*)xr;
    float4 p1 = *(const float4*)(xr + 4);
    union { ushort4 u4[2]; bf16x8 v; } fa;
    fa.u4[0] = make_ushort4(f2b(p0.x), f2b(p0.y), f2b(p0.z), f2b(p0.w));
    fa.u4[1] = make_ushort4(f2b(p1.x), f2b(p1.y), f2b(p1.z), f2b(p1.w));
    const u16* pb = P + ((kt * 8) * 64 + lane) * 8;
#pragma unroll
    for (int nt = 0; nt < 8; nt++) {
      bf16x8 bf = *(const bf16x8*)(pb + nt * 512);
      acc[nt] = __builtin_amdgcn_mfma_f32_16x16x32_bf16(fa.v, bf, acc[nt], 0, 0, 0);
    }
  }
#pragma unroll
  for (int nt = 0; nt < 8; nt++) {
    int c = nt * 16 + l15;
    float b = bias[c];
#pragma unroll
    for (int r = 0; r < 4; r++)
      zb[(w * 16 + quad * 4 + r) * 132 + c] = acc[nt][r] + b;
  }
  __syncthreads();
  int r = lane >> 2, seg = lane & 3;
  long grow = m0 + w * 16 + r;
  if (grow < M) {
    const float* zrow = &zb[(w * 16 + r) * 132 + seg * 32];
    u16* ip = inp + grow * 128 + seg * 32;
    u16* hp = hout + grow * 128 + seg * 32;
    u8*  qp = h8out + grow * 128 + seg * 32;
#pragma unroll
    for (int b = 0; b < 4; b++) {
      float zv[8];
      *(float4*)&zv[0] = *(const float4*)(zrow + b * 8);
      *(float4*)&zv[4] = *(const float4*)(zrow + b * 8 + 4);
      float rv[8];
#pragma unroll
      for (int jj = 0; jj < 8; jj++) rv[jj] = fmaxf(zv[jj], 0.f);
      *(ushort4*)(ip + b * 8)     = make_ushort4(f2b(zv[0]), f2b(zv[1]), f2b(zv[2]), f2b(zv[3]));
      *(ushort4*)(ip + b * 8 + 4) = make_ushort4(f2b(zv[4]), f2b(zv[5]), f2b(zv[6]), f2b(zv[7]));
      *(ushort4*)(hp + b * 8)     = make_ushort4(f2b(rv[0]), f2b(rv[1]), f2b(rv[2]), f2b(rv[3]));
      *(ushort4*)(hp + b * 8 + 4) = make_ushort4(f2b(rv[4]), f2b(rv[5]), f2b(rv[6]), f2b(rv[7]));
      unsigned q0 = 0, q1 = 0;
      q0 = __builtin_amdgcn_cvt_pk_fp8_f32(rv[0], rv[1], q0, false);
      q0 = __builtin_amdgcn_cvt_pk_fp8_f32(rv[2], rv[3], q0, true);
      q1 = __builtin_amdgcn_cvt_pk_fp8_f32(rv[4], rv[5], q1, false);
      q1 = __builtin_amdgcn_cvt_pk_fp8_f32(rv[6], rv[7], q1, true);
      *(uint2*)(qp + b * 8) = make_uint2(q0, q1);
    }
  }
}

// ------- output projection: gl = h@WloT (PLANE-major), gr = h@WroT (row-major) -------
__global__ __launch_bounds__(256) void out_proj_k(
    const u16* __restrict__ A, const u16* __restrict__ PLO,
    const u16* __restrict__ PRO, u16* __restrict__ gl, u16* __restrict__ gr, int M) {
  __shared__ float zb[64 * 132];
  int tid = threadIdx.x;
  int w = tid >> 6, lane = tid & 63;
  int quad = lane >> 4, l15 = lane & 15;
  int m0 = blockIdx.x * 64;
  int rowa = m0 + w * 16 + l15; if (rowa > M - 1) rowa = M - 1;
  f32x4 acc[8] = {};
#pragma unroll
  for (int kt = 0; kt < 4; kt++) {
    bf16x8 af = *(const bf16x8*)(A + (long)rowa * 128 + kt * 32 + quad * 8);
#pragma unroll
    for (int nt = 0; nt < 4; nt++) {
      bf16x8 b0 = *(const bf16x8*)(PLO + ((kt * 4 + nt) * 64 + lane) * 8);
      bf16x8 b1 = *(const bf16x8*)(PRO + ((kt * 4 + nt) * 64 + lane) * 8);
      acc[nt]     = __builtin_amdgcn_mfma_f32_16x16x32_bf16(af, b0, acc[nt], 0, 0, 0);
      acc[4 + nt] = __builtin_amdgcn_mfma_f32_16x16x32_bf16(af, b1, acc[4 + nt], 0, 0, 0);
    }
  }
  // zb cols 0-63 = gl, 64-127 = gr
#pragma unroll
  for (int nt = 0; nt < 4; nt++) {
    int c = nt * 16 + l15;
#pragma unroll
    for (int r = 0; r < 4; r++) {
      zb[(w * 16 + quad * 4 + r) * 132 + c]      = acc[nt][r];
      zb[(w * 16 + quad * 4 + r) * 132 + 64 + c] = acc[4 + nt][r];
    }
  }
  __syncthreads();
  int r = lane >> 2, seg = lane & 3;
  long grow = m0 + w * 16 + r;
  if (grow < M) {
    const float* zrow = &zb[(w * 16 + r) * 132 + seg * 32];
#pragma unroll
    for (int b = 0; b < 4; b++) {
      float zv[8];
      *(float4*)&zv[0] = *(const float4*)(zrow + b * 8);
      *(float4*)&zv[4] = *(const float4*)(zrow + b * 8 + 4);
      u16* dp;
      if (seg < 2) {
        int plane = seg * 2 + (b >> 1);
        dp = gl + (size_t)plane * (N_NODES * 16) + grow * 16 + (b & 1) * 8;
      } else {
        dp = gr + grow * 64 + (seg - 2) * 32 + b * 8;
      }
      *(ushort4*)(dp)     = make_ushort4(f2b(zv[0]), f2b(zv[1]), f2b(zv[2]), f2b(zv[3]));
      *(ushort4*)(dp + 4) = make_ushort4(f2b(zv[4]), f2b(zv[5]), f2b(zv[6]), f2b(zv[7]));
    }
  }
}

extern "C" void kernel_launch(void* const* d_in, const int* in_sizes, int n_in,
                              void* d_out, int out_size, void* d_ws, size_t ws_size,
                              hipStream_t stream) {
  if (ws_size < (size_t)WS_NEEDED) return;
  const float* x   = (const float*)d_in[0];
  const int*   ei  = (const int*)d_in[1];
  const float* Wp  = (const float*)d_in[2];
  const float* bp  = (const float*)d_in[3];
  const float* Wl  = (const float*)d_in[4];
  const float* bl  = (const float*)d_in[5];
  const float* Wr  = (const float*)d_in[6];
  const float* Wlo = (const float*)d_in[7];
  const float* blo = (const float*)d_in[8];
  const float* Wro = (const float*)d_in[9];
  float* out = (float*)d_out;
  char* ws = (char*)d_ws;
  int*   rp     = (int*)(ws + OFF_RP);
  float* invdeg = (float*)(ws + OFF_INVDEG);
  int*   bhist  = (int*)(ws + OFF_BHIST);
  int*   bbase  = (int*)(ws + OFF_BBASE);
  int*   gcur   = (int*)(ws + OFF_GCUR);
  uint2* pairs  = (uint2*)(ws + OFF_PAIRS);
  int*   col    = (int*)(ws + OFF_COL);
  u16*   pack   = (u16*)(ws + OFF_PACK);
  u16*   inp    = (u16*)(ws + OFF_INP);
  u16*   h      = (u16*)(ws + OFF_H);
  u8*    h8a    = (u8*)(ws + OFF_H8A);
  u8*    h8b    = (u8*)(ws + OFF_H8B);
  u16*   gl     = (u16*)(ws + OFF_GL);
  u16*   gr     = (u16*)(ws + OFF_GR);
  float* partial = (float*)(ws + OFF_MEAN);
  const int* srcv = ei;
  const int* dstv = ei + N_EDGES;

  hipMemsetAsync(ws + OFF_BHIST, 0, OFF_PAIRS - OFF_BHIST, stream);
  pack_weights_k<<<64, 256, 0, stream>>>(Wp, Wl, Wr, Wlo, Wro, pack);
  bhist_k<<<391, 256, 0, stream>>>(dstv, bhist);
  bscan_k<<<1, 512, 0, stream>>>(bhist, bbase, gcur, rp);
  part_k<<<NPBLK, 256, 0, stream>>>(srcv, dstv, gcur, pairs);
  csr_k<<<NBUK, 256, 0, stream>>>(pairs, bbase, rp, invdeg, col);

  int gblk = (N_NODES + 63) / 64;
  int fblk = (N_NODES + 7) / 8;

  inproj_mfma_k<<<gblk, 256, 0, stream>>>(x, pack + PK_WP, bp, inp, h, h8a, N_NODES);

  sage_fused_k<<<gblk, 256, 0, stream>>>(h8a, rp, col, invdeg,
                                         pack + PK_WL, h, pack + PK_WR,
                                         bl, inp, h, h8b, N_NODES);
  sage_fused_k<<<gblk, 256, 0, stream>>>(h8b, rp, col, invdeg,
                                         pack + PK_WL + 16384, h, pack + PK_WR + 16384,
                                         bl + 128, inp, h, h8a, N_NODES);
  sage_fused_k<<<gblk, 256, 0, stream>>>(h8a, rp, col, invdeg,
                                         pack + PK_WL + 32768, h, pack + PK_WR + 32768,
                                         bl + 256, inp, h, (u8*)nullptr, N_NODES);

  out_proj_k<<<gblk, 256, 0, stream>>>(h, pack + PK_WLO, pack + PK_WRO, gl, gr, N_NODES);
  out_gather16_k<<<PBLK16, 256, 0, stream>>>(gl, rp, col, invdeg, partial);
  out_softmax_k<<<fblk, 256, 0, stream>>>(partial, gr, blo, out);
}

// Round 15
// 534.973 us; speedup vs baseline: 1.2392x; 1.0143x over previous
//
#include <hip/hip_runtime.h>
#include <math.h>

#define N_NODES 100000
#define N_EDGES 1600000
#define NBUK 391          // ceil(N/256) buckets of 256 consecutive dst nodes
#define PCHUNK 8192       // edges per partition block
#define NPBLK 196         // ceil(E/PCHUNK)
#define PBLK16 3128       // 8 XCD-slots: 4 planes x 782 chunks of 128 nodes (out_gather)
#define GBLK 1563         // ceil(N/64) MFMA row-blocks

typedef unsigned short u16;
typedef unsigned char u8;
typedef __bf16 bf16x8 __attribute__((ext_vector_type(8)));
typedef float f32x4 __attribute__((ext_vector_type(4)));
typedef float f32x2 __attribute__((ext_vector_type(2)));

// ---- workspace layout (bytes), 16B-aligned ----
#define OFF_RP      0u          // int[N+1]
#define OFF_INVDEG  400016u     // float[N]
#define OFF_BHIST   800016u     // int[392]
#define OFF_BBASE   801600u     // int[392]
#define OFF_GCUR    803200u     // int[391]
#define OFF_PCTR    804800u     // int[64] (unused, layout stability)
#define OFF_PAIRS   805056u     // uint2[E] = 12.8 MB
#define OFF_COL     13605056u   // int[E]
#define OFF_PACK    20005056u   // u16[131072] packed bf16 weight fragments
#define OFF_INP     20267200u   // u16[N*128] residual (pre-relu inProj), bf16
#define OFF_H       45867200u   // u16[N*128] h (in-place across layers), bf16, row-major
#define OFF_H8A     71467200u   // u8[N][128] fp8 copy of h, ROW-major, buffer A
#define OFF_H8B     84267200u   // u8[N][128] fp8 copy, ROW-major, buffer B
#define OFF_GL      97067200u   // u16[4][N][16] projected neighbor logits, PLANE-major bf16
#define OFF_GR      109867200u  // u16[N*64] projected root logits, bf16, row-major
#define OFF_MEAN    122667200u  // float[N][64] partial for output stage
#define WS_NEEDED   148267200u

// packed-weight element offsets (u16 units)
#define PK_WP   0
#define PK_WL   16384
#define PK_WR   65536
#define PK_WLO  114688
#define PK_WRO  122880

__device__ __forceinline__ float bfl(unsigned u) {
  union { unsigned i; float f; } v; v.i = u << 16; return v.f;
}
__device__ __forceinline__ float bfh(unsigned u) {
  union { unsigned i; float f; } v; v.i = u & 0xFFFF0000u; return v.f;
}
__device__ __forceinline__ u16 f2b(float f) {       // RTNE
  union { float f; unsigned i; } v; v.f = f;
  unsigned r = (v.i + 0x7FFFu + ((v.i >> 16) & 1u)) >> 16;
  return (u16)r;
}

// ---------------- PROLOGUE (role-split): bhist (blocks 0..390) | pack (391..454) ----------------
__global__ __launch_bounds__(256) void prologue_k(
    const int* __restrict__ dst, int* __restrict__ bhist,
    const float* __restrict__ Wp, const float* __restrict__ Wl,
    const float* __restrict__ Wr, const float* __restrict__ Wlo,
    const float* __restrict__ Wro, u16* __restrict__ P) {
  __shared__ int lc[NBUK];
  int b = blockIdx.x;
  int t = threadIdx.x;
  if (b < NBUK) {
    // ---- bhist role ----
    for (int i = t; i < NBUK; i += 256) lc[i] = 0;
    __syncthreads();
    int base = b * 4096;
#pragma unroll
    for (int r = 0; r < 16; r++) {
      int i = base + r * 256 + t;
      if (i < N_EDGES) atomicAdd(&lc[dst[i] >> 8], 1);
    }
    __syncthreads();
    for (int i = t; i < NBUK; i += 256)
      if (lc[i]) atomicAdd(&bhist[i], lc[i]);
    return;
  }
  // ---- pack role ----
  int tt = (b - NBUK) * 256 + t;
  if (tt >= 16384) return;
  const float* W; u16* dstp; int j; int NT;
  if (tt < 2048)        { W = Wp;                     dstp = P + PK_WP;               j = tt;                 NT = 8; }
  else if (tt < 8192)   { int m = (tt - 2048) >> 11;  j = (tt - 2048) & 2047;
                          W = Wl + (m << 14);         dstp = P + PK_WL + (m << 14);   NT = 8; }
  else if (tt < 14336)  { int m = (tt - 8192) >> 11;  j = (tt - 8192) & 2047;
                          W = Wr + (m << 14);         dstp = P + PK_WR + (m << 14);   NT = 8; }
  else if (tt < 15360)  { j = tt - 14336;             W = Wlo;  dstp = P + PK_WLO;    NT = 4; }
  else                  { j = tt - 15360;             W = Wro;  dstp = P + PK_WRO;    NT = 4; }
  int lane = j & 63;
  int nt, kt;
  if (NT == 8) { nt = (j >> 6) & 7; kt = j >> 9; }
  else         { nt = (j >> 6) & 3; kt = j >> 8; }
  int n  = nt * 16 + (lane & 15);
  int k0 = kt * 32 + ((lane >> 4) << 3);
  const float* s = W + n * 128 + k0;
  ushort4 lo = make_ushort4(f2b(s[0]), f2b(s[1]), f2b(s[2]), f2b(s[3]));
  ushort4 hi = make_ushort4(f2b(s[4]), f2b(s[5]), f2b(s[6]), f2b(s[7]));
  *(ushort4*)(dstp + j * 8)     = lo;
  *(ushort4*)(dstp + j * 8 + 4) = hi;
}

// ---------- single-block scan of bucket counts ----------
__global__ __launch_bounds__(512) void bscan_k(const int* __restrict__ bhist,
                                               int* __restrict__ bbase,
                                               int* __restrict__ gcur,
                                               int* __restrict__ rp) {
  __shared__ int s[512];
  int t = threadIdx.x;
  int v = (t < NBUK) ? bhist[t] : 0;
  s[t] = v;
  __syncthreads();
  for (int off = 1; off < 512; off <<= 1) {
    int u = (t >= off) ? s[t - off] : 0;
    __syncthreads();
    s[t] += u;
    __syncthreads();
  }
  if (t < NBUK) { int e = s[t] - v; bbase[t] = e; gcur[t] = e; }
  if (t == NBUK - 1) { bbase[NBUK] = s[t]; rp[N_NODES] = s[t]; }
}

// ---------- partition edges into bucket-contiguous (src,dst) pairs ----------
__global__ __launch_bounds__(256) void part_k(const int* __restrict__ src,
                                              const int* __restrict__ dst,
                                              int* __restrict__ gcur,
                                              uint2* __restrict__ pairs) {
  __shared__ int lcnt[NBUK + 1];
  __shared__ int lofs[512];
  __shared__ int cur[NBUK];
  __shared__ int gslot[NBUK];
  __shared__ uint2 stag[PCHUNK];
  int t = threadIdx.x;
  for (int i = t; i < NBUK + 1; i += 256) lcnt[i] = 0;
  __syncthreads();
  int base = blockIdx.x * PCHUNK;
#pragma unroll
  for (int r = 0; r < PCHUNK / 256; r++) {
    int i = base + r * 256 + t;
    if (i < N_EDGES) atomicAdd(&lcnt[dst[i] >> 8], 1);
  }
  __syncthreads();
  {
    int e1 = t + 256;
    lofs[t]  = (t  <= NBUK) ? lcnt[t]  : 0;
    lofs[e1] = (e1 <= NBUK) ? lcnt[e1] : 0;
    __syncthreads();
    for (int off = 1; off < 512; off <<= 1) {
      int a0 = (t  >= off) ? lofs[t  - off] : 0;
      int a1 = (e1 >= off) ? lofs[e1 - off] : 0;
      __syncthreads();
      lofs[t] += a0; lofs[e1] += a1;
      __syncthreads();
    }
    int o0 = lofs[t]  - ((t  <= NBUK) ? lcnt[t]  : 0);
    int o1 = lofs[e1] - ((e1 <= NBUK) ? lcnt[e1] : 0);
    __syncthreads();
    lofs[t] = o0; lofs[e1] = o1;
    __syncthreads();
  }
  for (int i = t; i < NBUK; i += 256) cur[i] = lofs[i];
  __syncthreads();
#pragma unroll
  for (int r = 0; r < PCHUNK / 256; r++) {
    int i = base + r * 256 + t;
    if (i < N_EDGES) {
      int d = dst[i];
      int slot = atomicAdd(&cur[d >> 8], 1);
      stag[slot] = make_uint2((unsigned)src[i], (unsigned)d);
    }
  }
  __syncthreads();
  for (int i = t; i < NBUK; i += 256)
    if (lcnt[i]) gslot[i] = atomicAdd(&gcur[i], lcnt[i]);
  __syncthreads();
  int total = lofs[NBUK];
  for (int p = t; p < total; p += 256) {
    uint2 pr = stag[p];
    int b = (int)(pr.y >> 8);
    pairs[gslot[b] + (p - lofs[b])] = pr;
  }
}

// ---------------- MID (role-split): inproj (blocks 0..1562) | csr (1563..1953) ----------------
// inproj depends only on {x, pack} (done); csr depends only on {pairs, bbase} (done).
// The ~35us inproj hides the ~20us csr under one launch. Shared zb reused by csr as int scratch.
__global__ __launch_bounds__(256) void mid_k(
    const uint2* __restrict__ pairs, const int* __restrict__ bbase,
    int* __restrict__ rp, float* __restrict__ invdeg, int* __restrict__ col,
    const float* __restrict__ X, const u16* __restrict__ P,
    const float* __restrict__ bias,
    u16* __restrict__ inp, u16* __restrict__ hout, u8* __restrict__ h8out, int M) {
  __shared__ float zb[64 * 132];
  int tid = threadIdx.x;
  int blk = blockIdx.x;
  if (blk >= GBLK) {
    // ---- csr role ----
    int* cnt = (int*)zb;
    int* scn = cnt + 256;
    int* cur = scn + 256;
    int b = blk - GBLK, t = tid;
    int lo = bbase[b], hi = bbase[b + 1];
    cnt[t] = 0;
    __syncthreads();
    for (int p = lo + t; p < hi; p += 256)
      atomicAdd(&cnt[pairs[p].y & 255], 1);
    __syncthreads();
    int c = cnt[t];
    scn[t] = c;
    __syncthreads();
    for (int off = 1; off < 256; off <<= 1) {
      int v = (t >= off) ? scn[t - off] : 0;
      __syncthreads();
      scn[t] += v;
      __syncthreads();
    }
    int excl = scn[t] - c;
    int node = (b << 8) + t;
    if (node < N_NODES) {
      rp[node] = lo + excl;
      invdeg[node] = 1.0f / (float)(c > 1 ? c : 1);
    }
    cur[t] = lo + excl;
    __syncthreads();
    for (int p = lo + t; p < hi; p += 256) {
      uint2 pr = pairs[p];
      int slot = atomicAdd(&cur[pr.y & 255], 1);
      col[slot] = (int)pr.x;
    }
    return;
  }
  // ---- inproj role ----
  int w = tid >> 6, lane = tid & 63;
  int quad = lane >> 4, l15 = lane & 15;
  int m0 = blk * 64;
  int rowa = m0 + w * 16 + l15; if (rowa > M - 1) rowa = M - 1;
  f32x4 acc[8] = {};
#pragma unroll
  for (int kt = 0; kt < 4; kt++) {
    const float* xr = X + (long)rowa * 128 + kt * 32 + quad * 8;
    float4 p0 = *(const float4*)xr;
    float4 p1 = *(const float4*)(xr + 4);
    union { ushort4 u4[2]; bf16x8 v; } fa;
    fa.u4[0] = make_ushort4(f2b(p0.x), f2b(p0.y), f2b(p0.z), f2b(p0.w));
    fa.u4[1] = make_ushort4(f2b(p1.x), f2b(p1.y), f2b(p1.z), f2b(p1.w));
    const u16* pb = P + ((kt * 8) * 64 + lane) * 8;
#pragma unroll
    for (int nt = 0; nt < 8; nt++) {
      bf16x8 bf = *(const bf16x8*)(pb + nt * 512);
      acc[nt] = __builtin_amdgcn_mfma_f32_16x16x32_bf16(fa.v, bf, acc[nt], 0, 0, 0);
    }
  }
#pragma unroll
  for (int nt = 0; nt < 8; nt++) {
    int c = nt * 16 + l15;
    float b = bias[c];
#pragma unroll
    for (int r = 0; r < 4; r++)
      zb[(w * 16 + quad * 4 + r) * 132 + c] = acc[nt][r] + b;
  }
  __syncthreads();
  int r = lane >> 2, seg = lane & 3;
  long grow = m0 + w * 16 + r;
  if (grow < M) {
    const float* zrow = &zb[(w * 16 + r) * 132 + seg * 32];
    u16* ip = inp + grow * 128 + seg * 32;
    u16* hp = hout + grow * 128 + seg * 32;
    u8*  qp = h8out + grow * 128 + seg * 32;
#pragma unroll
    for (int b = 0; b < 4; b++) {
      float zv[8];
      *(float4*)&zv[0] = *(const float4*)(zrow + b * 8);
      *(float4*)&zv[4] = *(const float4*)(zrow + b * 8 + 4);
      float rv[8];
#pragma unroll
      for (int jj = 0; jj < 8; jj++) rv[jj] = fmaxf(zv[jj], 0.f);
      *(ushort4*)(ip + b * 8)     = make_ushort4(f2b(zv[0]), f2b(zv[1]), f2b(zv[2]), f2b(zv[3]));
      *(ushort4*)(ip + b * 8 + 4) = make_ushort4(f2b(zv[4]), f2b(zv[5]), f2b(zv[6]), f2b(zv[7]));
      *(ushort4*)(hp + b * 8)     = make_ushort4(f2b(rv[0]), f2b(rv[1]), f2b(rv[2]), f2b(rv[3]));
      *(ushort4*)(hp + b * 8 + 4) = make_ushort4(f2b(rv[4]), f2b(rv[5]), f2b(rv[6]), f2b(rv[7]));
      unsigned q0 = 0, q1 = 0;
      q0 = __builtin_amdgcn_cvt_pk_fp8_f32(rv[0], rv[1], q0, false);
      q0 = __builtin_amdgcn_cvt_pk_fp8_f32(rv[2], rv[3], q0, true);
      q1 = __builtin_amdgcn_cvt_pk_fp8_f32(rv[4], rv[5], q1, false);
      q1 = __builtin_amdgcn_cvt_pk_fp8_f32(rv[6], rv[7], q1, true);
      *(uint2*)(qp + b * 8) = make_uint2(q0, q1);
    }
  }
}

// ------- FUSED SAGE: gather-mean (phase 1, LDS) + MFMA + epilogue (one block = 64 nodes) -------
__global__ __launch_bounds__(256) void sage_fused_k(
    const u8* __restrict__ h8, const int* __restrict__ rp,
    const int* __restrict__ col, const float* __restrict__ invdeg,
    const u16* __restrict__ P0, const u16* __restrict__ A1,
    const u16* __restrict__ P1, const float* __restrict__ bias,
    const u16* __restrict__ inp, u16* __restrict__ outp,
    u8* __restrict__ h8out, int M) {
  __shared__ float zb[64 * 132];          // 33792 B
  u16* meanl = (u16*)zb;                  // [64][136] bf16 overlay, freed pre-zb
  int tid = threadIdx.x;
  int m0 = blockIdx.x * 64;
  {
    int grp = tid >> 3, lane8 = tid & 7;
    const u8* hp = h8 + lane8 * 16;
#pragma unroll
    for (int half = 0; half < 2; half++) {
      int lrow = half * 32 + grp;
      int node = m0 + lrow; if (node > M - 1) node = M - 1;
      int beg = rp[node], end = rp[node + 1];
      float a[16];
#pragma unroll
      for (int i = 0; i < 16; i++) a[i] = 0.f;
      for (int j = beg; j < end; j += 8) {
        int ci = 0;
        if (j + lane8 < end) ci = col[j + lane8];
        int cnt = end - j;
#pragma unroll
        for (int e = 0; e < 8; e++) {
          if (e < cnt) {
            int s = __shfl(ci, e, 8);
            uint4 v = *(const uint4*)(hp + (size_t)(unsigned)s * 128);
            f32x2 p0 = __builtin_amdgcn_cvt_pk_f32_fp8(v.x, false);
            f32x2 p1 = __builtin_amdgcn_cvt_pk_f32_fp8(v.x, true);
            f32x2 p2 = __builtin_amdgcn_cvt_pk_f32_fp8(v.y, false);
            f32x2 p3 = __builtin_amdgcn_cvt_pk_f32_fp8(v.y, true);
            f32x2 p4 = __builtin_amdgcn_cvt_pk_f32_fp8(v.z, false);
            f32x2 p5 = __builtin_amdgcn_cvt_pk_f32_fp8(v.z, true);
            f32x2 p6 = __builtin_amdgcn_cvt_pk_f32_fp8(v.w, false);
            f32x2 p7 = __builtin_amdgcn_cvt_pk_f32_fp8(v.w, true);
            a[0]  += p0[0]; a[1]  += p0[1]; a[2]  += p1[0]; a[3]  += p1[1];
            a[4]  += p2[0]; a[5]  += p2[1]; a[6]  += p3[0]; a[7]  += p3[1];
            a[8]  += p4[0]; a[9]  += p4[1]; a[10] += p5[0]; a[11] += p5[1];
            a[12] += p6[0]; a[13] += p6[1]; a[14] += p7[0]; a[15] += p7[1];
          }
        }
      }
      float wd = invdeg[node];
      u16* mp = meanl + lrow * 136 + lane8 * 16;
      *(ushort4*)(mp)      = make_ushort4(f2b(a[0]*wd),  f2b(a[1]*wd),  f2b(a[2]*wd),  f2b(a[3]*wd));
      *(ushort4*)(mp + 4)  = make_ushort4(f2b(a[4]*wd),  f2b(a[5]*wd),  f2b(a[6]*wd),  f2b(a[7]*wd));
      *(ushort4*)(mp + 8)  = make_ushort4(f2b(a[8]*wd),  f2b(a[9]*wd),  f2b(a[10]*wd), f2b(a[11]*wd));
      *(ushort4*)(mp + 12) = make_ushort4(f2b(a[12]*wd), f2b(a[13]*wd), f2b(a[14]*wd), f2b(a[15]*wd));
    }
  }
  __syncthreads();
  int w = tid >> 6, lane = tid & 63;
  int quad = lane >> 4, l15 = lane & 15;
  int rowa = m0 + w * 16 + l15; if (rowa > M - 1) rowa = M - 1;
  int lrowa = w * 16 + l15;
  f32x4 acc[8] = {};
#pragma unroll
  for (int kt = 0; kt < 4; kt++) {
    bf16x8 am = *(const bf16x8*)(meanl + lrowa * 136 + kt * 32 + quad * 8);
    bf16x8 ar = *(const bf16x8*)(A1 + (long)rowa * 128 + kt * 32 + quad * 8);
    const u16* pl = P0 + ((kt * 8) * 64 + lane) * 8;
    const u16* pr = P1 + ((kt * 8) * 64 + lane) * 8;
#pragma unroll
    for (int nt = 0; nt < 8; nt++) {
      bf16x8 b0 = *(const bf16x8*)(pl + nt * 512);
      bf16x8 b1 = *(const bf16x8*)(pr + nt * 512);
      acc[nt] = __builtin_amdgcn_mfma_f32_16x16x32_bf16(am, b0, acc[nt], 0, 0, 0);
      acc[nt] = __builtin_amdgcn_mfma_f32_16x16x32_bf16(ar, b1, acc[nt], 0, 0, 0);
    }
  }
  __syncthreads();
#pragma unroll
  for (int nt = 0; nt < 8; nt++) {
    int c = nt * 16 + l15;
    float b = bias[c];
#pragma unroll
    for (int r = 0; r < 4; r++)
      zb[(w * 16 + quad * 4 + r) * 132 + c] = fmaxf(acc[nt][r] + b, 0.f);
  }
  __syncthreads();
  int r = lane >> 2, seg = lane & 3;
  long grow = m0 + w * 16 + r;
  if (grow < M) {
    const float* zrow = &zb[(w * 16 + r) * 132 + seg * 32];
    const u16* ip = inp + grow * 128 + seg * 32;
    u16* op = outp + grow * 128 + seg * 32;
#pragma unroll
    for (int b = 0; b < 4; b++) {
      float zv[8];
      *(float4*)&zv[0] = *(const float4*)(zrow + b * 8);
      *(float4*)&zv[4] = *(const float4*)(zrow + b * 8 + 4);
      uint2 iv0 = *(const uint2*)(ip + b * 8);
      uint2 iv1 = *(const uint2*)(ip + b * 8 + 4);
      float fv[8];
      fv[0] = zv[0] + 0.2f * bfl(iv0.x); fv[1] = zv[1] + 0.2f * bfh(iv0.x);
      fv[2] = zv[2] + 0.2f * bfl(iv0.y); fv[3] = zv[3] + 0.2f * bfh(iv0.y);
      fv[4] = zv[4] + 0.2f * bfl(iv1.x); fv[5] = zv[5] + 0.2f * bfh(iv1.x);
      fv[6] = zv[6] + 0.2f * bfl(iv1.y); fv[7] = zv[7] + 0.2f * bfh(iv1.y);
      *(ushort4*)(op + b * 8)     = make_ushort4(f2b(fv[0]), f2b(fv[1]), f2b(fv[2]), f2b(fv[3]));
      *(ushort4*)(op + b * 8 + 4) = make_ushort4(f2b(fv[4]), f2b(fv[5]), f2b(fv[6]), f2b(fv[7]));
      if (h8out) {
        unsigned q0 = 0, q1 = 0;
        q0 = __builtin_amdgcn_cvt_pk_fp8_f32(fv[0], fv[1], q0, false);
        q0 = __builtin_amdgcn_cvt_pk_fp8_f32(fv[2], fv[3], q0, true);
        q1 = __builtin_amdgcn_cvt_pk_fp8_f32(fv[4], fv[5], q1, false);
        q1 = __builtin_amdgcn_cvt_pk_fp8_f32(fv[6], fv[7], q1, true);
        *(uint2*)(h8out + grow * 128 + seg * 32 + b * 8) = make_uint2(q0, q1);
      }
    }
  }
}

// ------- plane-major gather of gl (16ch bf16 = 32B rows): 2 lanes x 16B -------
__global__ __launch_bounds__(256) void out_gather16_k(
    const u16* __restrict__ gl, const int* __restrict__ rp,
    const int* __restrict__ col, const float* __restrict__ invdeg,
    float* __restrict__ partial) {
  int b = blockIdx.x;
  int plane = (b & 7) >> 1;
  int idx = ((b >> 3) << 1) + (b & 1);
  int tid = threadIdx.x;
  int grp = tid >> 1, lane2 = tid & 1;
  int node = idx * 128 + grp;
  if (node >= N_NODES) return;
  int beg = rp[node], end = rp[node + 1];
  const u16* gp = gl + (size_t)plane * (N_NODES * 16) + lane2 * 8;
  float a[8];
#pragma unroll
  for (int i = 0; i < 8; i++) a[i] = 0.f;
  int j = beg;
  for (; j + 8 <= end; j += 8) {
    int4 ci = *(const int4*)(col + j + lane2 * 4);
    int cia[4] = {ci.x, ci.y, ci.z, ci.w};
    uint4 v[8];
#pragma unroll
    for (int e = 0; e < 8; e++) {
      int s = __shfl(cia[e & 3], e >> 2, 2);
      v[e] = *(const uint4*)(gp + ((size_t)(unsigned)s << 4));
    }
#pragma unroll
    for (int e = 0; e < 8; e++) {
      a[0] += bfl(v[e].x); a[1] += bfh(v[e].x);
      a[2] += bfl(v[e].y); a[3] += bfh(v[e].y);
      a[4] += bfl(v[e].z); a[5] += bfh(v[e].z);
      a[6] += bfl(v[e].w); a[7] += bfh(v[e].w);
    }
  }
  for (; j < end; j++) {
    int s = col[j];
    uint4 vv = *(const uint4*)(gp + ((size_t)(unsigned)s << 4));
    a[0] += bfl(vv.x); a[1] += bfh(vv.x);
    a[2] += bfl(vv.y); a[3] += bfh(vv.y);
    a[4] += bfl(vv.z); a[5] += bfh(vv.z);
    a[6] += bfl(vv.w); a[7] += bfh(vv.w);
  }
  float wd = invdeg[node];
  float* pp = partial + (size_t)node * 64 + plane * 16 + lane2 * 8;
  *(float4*)(pp)     = make_float4(a[0]*wd, a[1]*wd, a[2]*wd, a[3]*wd);
  *(float4*)(pp + 4) = make_float4(a[4]*wd, a[5]*wd, a[6]*wd, a[7]*wd);
}

// ------- output softmax: out = log_softmax(partial + gr + blo), half-wave per node -------
__global__ __launch_bounds__(256) void out_softmax_k(
    const float* __restrict__ partial, const u16* __restrict__ gr,
    const float* __restrict__ blo, float* __restrict__ outp) {
  int node = blockIdx.x * 8 + (threadIdx.x >> 5);
  int lane = threadIdx.x & 31;
  if (node >= N_NODES) return;
  float2 pz = *(const float2*)(partial + (size_t)node * 64 + lane * 2);
  unsigned g = *(const unsigned*)(gr + (size_t)node * 64 + lane * 2);
  float z0 = pz.x + bfl(g) + blo[lane * 2];
  float z1 = pz.y + bfh(g) + blo[lane * 2 + 1];
  float mx = fmaxf(z0, z1);
#pragma unroll
  for (int off = 16; off >= 1; off >>= 1) mx = fmaxf(mx, __shfl_xor(mx, off, 32));
  float s = __expf(z0 - mx) + __expf(z1 - mx);
#pragma unroll
  for (int off = 16; off >= 1; off >>= 1) s += __shfl_xor(s, off, 32);
  float ro = mx + __logf(s);
  float2 o = make_float2(z0 - ro, z1 - ro);
  *(float2*)(outp + (size_t)node * 64 + lane * 2) = o;
}

// ------- output projection: gl = h@WloT (PLANE-major), gr = h@WroT (row-major) -------
__global__ __launch_bounds__(256) void out_proj_k(
    const u16* __restrict__ A, const u16* __restrict__ PLO,
    const u16* __restrict__ PRO, u16* __restrict__ gl, u16* __restrict__ gr, int M) {
  __shared__ float zb[64 * 132];
  int tid = threadIdx.x;
  int w = tid >> 6, lane = tid & 63;
  int quad = lane >> 4, l15 = lane & 15;
  int m0 = blockIdx.x * 64;
  int rowa = m0 + w * 16 + l15; if (rowa > M - 1) rowa = M - 1;
  f32x4 acc[8] = {};
#pragma unroll
  for (int kt = 0; kt < 4; kt++) {
    bf16x8 af = *(const bf16x8*)(A + (long)rowa * 128 + kt * 32 + quad * 8);
#pragma unroll
    for (int nt = 0; nt < 4; nt++) {
      bf16x8 b0 = *(const bf16x8*)(PLO + ((kt * 4 + nt) * 64 + lane) * 8);
      bf16x8 b1 = *(const bf16x8*)(PRO + ((kt * 4 + nt) * 64 + lane) * 8);
      acc[nt]     = __builtin_amdgcn_mfma_f32_16x16x32_bf16(af, b0, acc[nt], 0, 0, 0);
      acc[4 + nt] = __builtin_amdgcn_mfma_f32_16x16x32_bf16(af, b1, acc[4 + nt], 0, 0, 0);
    }
  }
  // zb cols 0-63 = gl, 64-127 = gr
#pragma unroll
  for (int nt = 0; nt < 4; nt++) {
    int c = nt * 16 + l15;
#pragma unroll
    for (int r = 0; r < 4; r++) {
      zb[(w * 16 + quad * 4 + r) * 132 + c]      = acc[nt][r];
      zb[(w * 16 + quad * 4 + r) * 132 + 64 + c] = acc[4 + nt][r];
    }
  }
  __syncthreads();
  int r = lane >> 2, seg = lane & 3;
  long grow = m0 + w * 16 + r;
  if (grow < M) {
    const float* zrow = &zb[(w * 16 + r) * 132 + seg * 32];
#pragma unroll
    for (int b = 0; b < 4; b++) {
      float zv[8];
      *(float4*)&zv[0] = *(const float4*)(zrow + b * 8);
      *(float4*)&zv[4] = *(const float4*)(zrow + b * 8 + 4);
      u16* dp;
      if (seg < 2) {
        int plane = seg * 2 + (b >> 1);
        dp = gl + (size_t)plane * (N_NODES * 16) + grow * 16 + (b & 1) * 8;
      } else {
        dp = gr + grow * 64 + (seg - 2) * 32 + b * 8;
      }
      *(ushort4*)(dp)     = make_ushort4(f2b(zv[0]), f2b(zv[1]), f2b(zv[2]), f2b(zv[3]));
      *(ushort4*)(dp + 4) = make_ushort4(f2b(zv[4]), f2b(zv[5]), f2b(zv[6]), f2b(zv[7]));
    }
  }
}

extern "C" void kernel_launch(void* const* d_in, const int* in_sizes, int n_in,
                              void* d_out, int out_size, void* d_ws, size_t ws_size,
                              hipStream_t stream) {
  if (ws_size < (size_t)WS_NEEDED) return;
  const float* x   = (const float*)d_in[0];
  const int*   ei  = (const int*)d_in[1];
  const float* Wp  = (const float*)d_in[2];
  const float* bp  = (const float*)d_in[3];
  const float* Wl  = (const float*)d_in[4];
  const float* bl  = (const float*)d_in[5];
  const float* Wr  = (const float*)d_in[6];
  const float* Wlo = (const float*)d_in[7];
  const float* blo = (const float*)d_in[8];
  const float* Wro = (const float*)d_in[9];
  float* out = (float*)d_out;
  char* ws = (char*)d_ws;
  int*   rp     = (int*)(ws + OFF_RP);
  float* invdeg = (float*)(ws + OFF_INVDEG);
  int*   bhist  = (int*)(ws + OFF_BHIST);
  int*   bbase  = (int*)(ws + OFF_BBASE);
  int*   gcur   = (int*)(ws + OFF_GCUR);
  uint2* pairs  = (uint2*)(ws + OFF_PAIRS);
  int*   col    = (int*)(ws + OFF_COL);
  u16*   pack   = (u16*)(ws + OFF_PACK);
  u16*   inp    = (u16*)(ws + OFF_INP);
  u16*   h      = (u16*)(ws + OFF_H);
  u8*    h8a    = (u8*)(ws + OFF_H8A);
  u8*    h8b    = (u8*)(ws + OFF_H8B);
  u16*   gl     = (u16*)(ws + OFF_GL);
  u16*   gr     = (u16*)(ws + OFF_GR);
  float* partial = (float*)(ws + OFF_MEAN);
  const int* srcv = ei;
  const int* dstv = ei + N_EDGES;

  int fblk = (N_NODES + 7) / 8;

  hipMemsetAsync(ws + OFF_BHIST, 0, OFF_PAIRS - OFF_BHIST, stream);
  prologue_k<<<NBUK + 64, 256, 0, stream>>>(dstv, bhist, Wp, Wl, Wr, Wlo, Wro, pack);
  bscan_k<<<1, 512, 0, stream>>>(bhist, bbase, gcur, rp);
  part_k<<<NPBLK, 256, 0, stream>>>(srcv, dstv, gcur, pairs);
  mid_k<<<GBLK + NBUK, 256, 0, stream>>>(pairs, bbase, rp, invdeg, col,
                                         x, pack + PK_WP, bp, inp, h, h8a, N_NODES);

  sage_fused_k<<<GBLK, 256, 0, stream>>>(h8a, rp, col, invdeg,
                                         pack + PK_WL, h, pack + PK_WR,
                                         bl, inp, h, h8b, N_NODES);
  sage_fused_k<<<GBLK, 256, 0, stream>>>(h8b, rp, col, invdeg,
                                         pack + PK_WL + 16384, h, pack + PK_WR + 16384,
                                         bl + 128, inp, h, h8a, N_NODES);
  sage_fused_k<<<GBLK, 256, 0, stream>>>(h8a, rp, col, invdeg,
                                         pack + PK_WL + 32768, h, pack + PK_WR + 32768,
                                         bl + 256, inp, h, (u8*)nullptr, N_NODES);

  out_proj_k<<<GBLK, 256, 0, stream>>>(h, pack + PK_WLO, pack + PK_WRO, gl, gr, N_NODES);
  out_gather16_k<<<PBLK16, 256, 0, stream>>>(gl, rp, col, invdeg, partial);
  out_softmax_k<<<fblk, 256, 0, stream>>>(partial, gr, blo, out);
}